// Round 13
// baseline (381.266 us; speedup 1.0000x reference)
//
#include <hip/hip_runtime.h>
#include <hip/hip_bf16.h>

#define B_ 16
#define N_ 577
#define C_ 1024
#define H_ 16
#define DH_ 64
#define M_ (B_*N_)          // 9232
#define KKEEP 144           // int(576 * 0.25)
#define VTP 584             // padded n-stride of transposed V
#define SST 325             // S row stride (dwords)

typedef __attribute__((ext_vector_type(8))) short bf16x8;
typedef __attribute__((ext_vector_type(4))) float f32x4;

// ---------------- helpers ----------------
__device__ __forceinline__ float b2f(unsigned short u){ return __uint_as_float(((unsigned int)u) << 16); }
__device__ __forceinline__ unsigned short f2bu(float f){
  __hip_bfloat16 h = __float2bfloat16(f);
  return *(unsigned short*)&h;
}
__device__ __forceinline__ float wredmaxf(float v){
  #pragma unroll
  for (int m=1;m<64;m<<=1) v = fmaxf(v, __shfl_xor(v, m, 64));
  return v;
}
__device__ __forceinline__ float wredsumf(float v){
  #pragma unroll
  for (int m=1;m<64;m<<=1) v += __shfl_xor(v, m, 64);
  return v;
}
// async global->LDS, 16B per lane; dest = uniform base + lane*16 (m104)
__device__ __forceinline__ void gload16(const unsigned short* g, unsigned short* l){
  __builtin_amdgcn_global_load_lds(
      (const __attribute__((address_space(1))) unsigned int*)g,
      (__attribute__((address_space(3))) unsigned int*)l,
      16, 0, 0);
}

// ---------------- kernel 0: fp32 -> bf16 pre-convert (X, qkv_w, proj_w) ----------------
__global__ __launch_bounds__(256) void cvt_bf16(
    const float* __restrict__ X, const float* __restrict__ Wq, const float* __restrict__ Wp,
    unsigned short* __restrict__ xb, unsigned short* __restrict__ wqb, unsigned short* __restrict__ wpb)
{
  size_t g = (size_t)blockIdx.x*256 + threadIdx.x;
  const float* src; unsigned short* dst; size_t off;
  if (g < 1181696){ src = X; dst = xb; off = g*8; }
  else if (g < 1574912){ src = Wq; dst = wqb; off = (g-1181696)*8; }
  else { src = Wp; dst = wpb; off = (g-1574912)*8; }
  float4 a = *(const float4*)(src+off), b = *(const float4*)(src+off+4);
  unsigned short t[8] = { f2bu(a.x), f2bu(a.y), f2bu(a.z), f2bu(a.w),
                          f2bu(b.x), f2bu(b.y), f2bu(b.z), f2bu(b.w) };
  *(uint4*)(dst+off) = *(uint4*)t;
}

// ---------------- kernel 1: QKV GEMM via MFMA + global_load_lds staging ----------------
// NOTE: q output is pre-scaled by 0.125 (exact 2^-3; attn uses raw scores)
__global__ __launch_bounds__(256) void gemm_qkv_mfma(
    const unsigned short* __restrict__ Xb, const unsigned short* __restrict__ Wb,
    unsigned short* __restrict__ qb, unsigned short* __restrict__ kb,
    unsigned short* __restrict__ vb)
{
  // BK=32: 64B LDS rows -> fragment ds_read_b128 banks are naturally balanced (no swizzle needed;
  // BK=64 would be a 16-way conflict per cdna §6-G4 and needs T2, incompatible with linear gload dest)
  __shared__ __align__(16) unsigned short As[128][32];
  __shared__ __align__(16) unsigned short Bs[128][32];
  const int tid = threadIdx.x;
  const int lane = tid & 63, wave = tid >> 6;
  const int wm = wave >> 1, wn = wave & 1;
  const int lr = lane & 15, kh = lane >> 4;
  const int bm = blockIdx.x*128, bn = blockIdx.y*128;

  const int idx0 = (wave*2+0)*64 + lane;
  const int idx1 = (wave*2+1)*64 + lane;
  const int r0 = idx0 >> 2, c0 = idx0 & 3;
  const int r1 = idx1 >> 2, c1 = idx1 & 3;
  const unsigned short* aS0 = Xb + (size_t)(bm + r0)*1024 + c0*8;
  const unsigned short* aS1 = Xb + (size_t)(bm + r1)*1024 + c1*8;
  const unsigned short* bS0 = Wb + (size_t)(bn + r0)*1024 + c0*8;
  const unsigned short* bS1 = Wb + (size_t)(bn + r1)*1024 + c1*8;
  unsigned short* aD0 = &As[0][0] + (wave*2+0)*512;
  unsigned short* aD1 = &As[0][0] + (wave*2+1)*512;
  unsigned short* bD0 = &Bs[0][0] + (wave*2+0)*512;
  unsigned short* bD1 = &Bs[0][0] + (wave*2+1)*512;

  const unsigned short* aR[4]; const unsigned short* bR[4];
  #pragma unroll
  for (int f=0; f<4; ++f){
    aR[f] = &As[wm*64 + f*16 + lr][kh*8];
    bR[f] = &Bs[wn*64 + f*16 + lr][kh*8];
  }

  f32x4 acc[4][4];
  #pragma unroll
  for (int i=0;i<4;++i)
    #pragma unroll
    for (int j=0;j<4;++j) acc[i][j] = (f32x4){0.f,0.f,0.f,0.f};

  for (int k0=0; k0<1024; k0+=32){
    __syncthreads();
    gload16(aS0 + k0, aD0);
    gload16(aS1 + k0, aD1);
    gload16(bS0 + k0, bD0);
    gload16(bS1 + k0, bD1);
    __syncthreads();
    bf16x8 af[4], bfr[4];
    #pragma unroll
    for (int f=0; f<4; ++f){
      af[f]  = *(const bf16x8*)aR[f];
      bfr[f] = *(const bf16x8*)bR[f];
    }
    __builtin_amdgcn_s_setprio(1);
    #pragma unroll
    for (int fm=0; fm<4; ++fm)
      #pragma unroll
      for (int fn=0; fn<4; ++fn)
        acc[fm][fn] = __builtin_amdgcn_mfma_f32_16x16x32_bf16(af[fm], bfr[fn], acc[fm][fn], 0,0,0);
    __builtin_amdgcn_s_setprio(0);
  }
  #pragma unroll
  for (int fm=0; fm<4; ++fm){
    #pragma unroll
    for (int j=0; j<4; ++j){
      int m = bm + wm*64 + fm*16 + kh*4 + j;
      if (m >= M_) continue;
      int b = m / N_, n = m - b*N_;
      #pragma unroll
      for (int fn=0; fn<4; ++fn){
        int c = bn + wn*64 + fn*16 + lr;
        int three = c >> 10, hh = (c >> 6) & 15, dd = c & 63;
        size_t off = ((size_t)(b*H_ + hh)*N_ + n)*DH_ + dd;
        if (three == 0)      qb[off] = f2bu(acc[fm][fn][j]*0.125f);   // folded softmax scale
        else if (three == 1) kb[off] = f2bu(acc[fm][fn][j]);
        else                 vb[off] = f2bu(acc[fm][fn][j]);
      }
    }
  }
}

// ---------------- kernel 1b: V transpose [bh][n][64] -> [bh][d][VTP] ----------------
__global__ __launch_bounds__(256) void transpose_v(
    const unsigned short* __restrict__ vb, unsigned short* __restrict__ vt)
{
  __shared__ unsigned short tile[64][72];
  const int t = threadIdx.x;
  const int bh = blockIdx.x / 10, nt = blockIdx.x % 10;
  const int n0 = nt*64;
  {
    int r = t >> 2, c0 = (t & 3) * 16;
    int n = n0 + r;
    uint4 a0={0,0,0,0}, a1={0,0,0,0};
    if (n < N_){
      const uint4* s = (const uint4*)(vb + ((size_t)bh*N_ + n)*DH_ + c0);
      a0 = s[0]; a1 = s[1];
    }
    *(uint4*)&tile[r][c0]   = a0;
    *(uint4*)&tile[r][c0+8] = a1;
  }
  __syncthreads();
  {
    int d = t & 63, j0 = (t >> 6) * 16;
    unsigned short v[16];
    #pragma unroll
    for (int i=0;i<16;++i) v[i] = tile[j0+i][d];
    unsigned short* dst = vt + ((size_t)bh*DH_ + d)*VTP + n0 + j0;
    if (n0 + j0 + 15 <= VTP-1){
      *(uint4*)dst     = *(uint4*)&v[0];
      *(uint4*)(dst+8) = *(uint4*)&v[8];
    } else if (n0 + j0 + 7 <= VTP-1){
      *(uint4*)dst = *(uint4*)&v[0];
    }
  }
}

// ---------------- kernel 2: fused attention (XCD-swizzled, scale pre-folded, setprio) ----------------
__global__ __launch_bounds__(256,6) void attn_kernel(
    const unsigned short* __restrict__ qw, const unsigned short* __restrict__ kw,
    const unsigned short* __restrict__ vt,
    const float* __restrict__ ucb, const int* __restrict__ counter_p,
    unsigned short* __restrict__ ctx, int* __restrict__ delta)
{
  __shared__ __align__(16) float S[16][SST];
  __shared__ float expl_s[584];
  __shared__ int   cnt_s[584];
  unsigned short (*pus)[584] = (unsigned short (*)[584])&S[0][0];

  const int tid = threadIdx.x;
  const int lane = tid & 63, wave = tid >> 6;
  const int lr = lane & 15, kh = lane >> 4;
  // XCD-aware bijective swizzle: nwg = 9472 = 8*1184; XCD x owns a contiguous chunk of (bh,tile)
  const int blk = (blockIdx.x & 7)*1184 + (blockIdx.x >> 3);
  const int bh = blk / 37, tileq = blk % 37;
  const int h = bh & 15;
  const int row0 = tileq * 16;

  const float logc = logf((float)(*counter_p) + 1.0f);
  for (int k2=tid; k2<N_; k2+=256){
    cnt_s[k2] = 0;
    expl_s[k2] = (k2==0) ? 0.f : sqrtf(logc / (ucb[h*N_ + k2] + 1e-6f));
  }

  const unsigned short* qbb = qw + (size_t)bh*N_*DH_;
  const unsigned short* kbb = kw + (size_t)bh*N_*DH_;
  bf16x8 aq0 = {0,0,0,0,0,0,0,0}, aq1 = {0,0,0,0,0,0,0,0};
  {
    int qr = row0 + lr;
    if (qr < N_){
      aq0 = *(const bf16x8*)(qbb + (size_t)qr*DH_ + kh*8);
      aq1 = *(const bf16x8*)(qbb + (size_t)qr*DH_ + 32 + kh*8);
    }
  }

  float acc[4][10];
  #pragma unroll
  for (int r=0;r<4;++r)
    #pragma unroll
    for (int s=0;s<10;++s) acc[r][s]=0.f;

  #pragma unroll
  for (int half=0; half<2; ++half){
    const int t0 = half ? 20 : 0, t1 = half ? 37 : 20, keyoff = half*320;
    for (int tile = t0 + wave; tile < t1; tile += 4){
      int keyr = tile*16 + lr;
      bf16x8 b0 = {0,0,0,0,0,0,0,0}, b1 = {0,0,0,0,0,0,0,0};
      if (keyr < N_){
        b0 = *(const bf16x8*)(kbb + (size_t)keyr*DH_ + kh*8);
        b1 = *(const bf16x8*)(kbb + (size_t)keyr*DH_ + 32 + kh*8);
      }
      f32x4 d = (f32x4){0.f,0.f,0.f,0.f};
      __builtin_amdgcn_s_setprio(1);
      d = __builtin_amdgcn_mfma_f32_16x16x32_bf16(aq0, b0, d, 0,0,0);
      d = __builtin_amdgcn_mfma_f32_16x16x32_bf16(aq1, b1, d, 0,0,0);
      __builtin_amdgcn_s_setprio(0);
      int col = tile*16 - keyoff + lr;
      #pragma unroll
      for (int rg=0; rg<4; ++rg)
        S[kh*4+rg][col] = d[rg];
    }
    __syncthreads();
    #pragma unroll
    for (int s=0; s<5; ++s){
      int sg = half*5 + s;
      int k = sg*64 + lane;
      if (k < N_){
        #pragma unroll
        for (int r=0;r<4;++r) acc[r][sg] = S[wave*4+r][k - keyoff];
      }
    }
    __syncthreads();
  }

  // ---- top-k (10-bit quantized ballot radix) + masked softmax + P store ----
  // scores already scaled by 0.125 (folded into q)
  #pragma unroll
  for (int r=0;r<4;++r){
    const int lrow = wave*4 + r;
    const int n = row0 + lrow;
    const bool rv = (n < N_);
    float uv[10]; bool vd[10];
    float mx0 = -3.4e38f, mn0 = 3.4e38f;
    #pragma unroll
    for (int s=0;s<10;++s){
      int k = s*64 + lane;
      vd[s] = (k >= 1) && (k < N_);
      uv[s] = acc[r][s] + (k < N_ ? expl_s[k] : 0.f);
      if (vd[s]){ mx0 = fmaxf(mx0, uv[s]); mn0 = fminf(mn0, uv[s]); }
    }
    const float mx1 = wredmaxf(mx0);
    const float mn1 = -wredmaxf(-mn0);
    const float scale = 1022.f / fmaxf(mx1 - mn1, 1e-30f);
    unsigned uq[10];
    #pragma unroll
    for (int s=0;s<10;++s)
      uq[s] = vd[s] ? (1u + (unsigned)((uv[s]-mn1)*scale)) : 0u;

    unsigned T = 0u;
    for (int bit=9; bit>=0; --bit){
      unsigned cand = T | (1u << bit);
      int c = 0;
      #pragma unroll
      for (int s=0;s<10;++s) c += (int)__popcll(__ballot(uq[s] >= cand));
      if (c >= KKEEP) T = cand;
    }
    int cgt = 0;
    #pragma unroll
    for (int s=0;s<10;++s) cgt += (int)__popcll(__ballot(uq[s] > T));
    const int rem = KKEEP - cgt;
    unsigned long long em[10];
    #pragma unroll
    for (int s=0;s<10;++s) em[s] = __ballot(uq[s] == T);
    const unsigned long long below = lane ? (~0ull >> (64 - lane)) : 0ull;
    bool keep[10];
    int pref = 0;
    #pragma unroll
    for (int s=0;s<10;++s){
      int k = s*64 + lane;
      bool kp2 = false;
      if (k == 0) kp2 = true;
      else if (k < N_){
        if (uq[s] > T) kp2 = true;
        else if (uq[s] == T) kp2 = (pref + __popcll(em[s] & below)) < rem;
      }
      keep[s] = kp2;
      pref += __popcll(em[s]);
    }
    float mxs = -3.4e38f;
    #pragma unroll
    for (int s=0;s<10;++s) if (keep[s]) mxs = fmaxf(mxs, acc[r][s]);
    mxs = wredmaxf(mxs);
    float p[10]; float den = 0.f;
    #pragma unroll
    for (int s=0;s<10;++s){ p[s] = keep[s] ? __expf(acc[r][s]-mxs) : 0.f; den += p[s]; }
    den = wredsumf(den);
    const float inv = 1.0f/den;
    #pragma unroll
    for (int s=0;s<10;++s){
      int k = s*64 + lane;
      if (k < N_) pus[lrow][k] = f2bu(p[s]*inv);
      if (rv && keep[s]) atomicAdd(&cnt_s[k < N_ ? k : 0], 1);
    }
  }
  __syncthreads();

  // ---- PV via MFMA ----
  {
    const int d0 = wave*16;
    const unsigned short* vtb = vt + ((size_t)bh*DH_ + d0 + lr)*VTP;
    f32x4 od = (f32x4){0.f,0.f,0.f,0.f};
    __builtin_amdgcn_s_setprio(1);
    #pragma unroll 3
    for (int kb2=0; kb2<18; ++kb2){
      bf16x8 pa  = *(const bf16x8*)&pus[lr][kb2*32 + kh*8];
      bf16x8 vb8 = *(const bf16x8*)(vtb + kb2*32 + kh*8);
      od = __builtin_amdgcn_mfma_f32_16x16x32_bf16(pa, vb8, od, 0,0,0);
    }
    __builtin_amdgcn_s_setprio(0);
    const float v576 = b2f(vtb[576]);
    #pragma unroll
    for (int rg=0; rg<4; ++rg){
      int q = kh*4 + rg;
      float o = fmaf(b2f(pus[q][576]), v576, od[rg]);
      int n0 = row0 + q;
      if (n0 < N_) ctx[((size_t)bh*N_ + n0)*DH_ + d0 + lr] = f2bu(o);
    }
  }
  __syncthreads();
  for (int k2=tid; k2<N_; k2+=256){
    int c2 = cnt_s[k2];
    if (c2) atomicAdd(&delta[h*N_ + k2], c2);
  }
}

// ---------------- kernel 3: output projection via MFMA + global_load_lds ----------------
__global__ __launch_bounds__(256) void gemm_proj_mfma(
    const unsigned short* __restrict__ ctxp, const unsigned short* __restrict__ Wb,
    const float* __restrict__ bias, float* __restrict__ out)
{
  __shared__ __align__(16) unsigned short As[128][32];
  __shared__ __align__(16) unsigned short Bs[128][32];
  const int tid = threadIdx.x;
  const int lane = tid & 63, wave = tid >> 6;
  const int wm = wave >> 1, wn = wave & 1;
  const int lr = lane & 15, kh = lane >> 4;
  const int bm = blockIdx.x*128, bn = blockIdx.y*128;

  const int idx0 = (wave*2+0)*64 + lane;
  const int idx1 = (wave*2+1)*64 + lane;
  const int r0 = idx0 >> 2, c0 = idx0 & 3;
  const int r1 = idx1 >> 2, c1 = idx1 & 3;
  const int m0r = bm + r0, m1r = bm + r1;
  const int b0 = m0r / N_, n0r = m0r - b0*N_;
  const int b1 = m1r / N_, n1r = m1r - b1*N_;
  const unsigned short* aBase0 = ctxp + ((size_t)b0*H_*N_ + n0r)*DH_ + c0*8;
  const unsigned short* aBase1 = ctxp + ((size_t)b1*H_*N_ + n1r)*DH_ + c1*8;
  const unsigned short* bS0 = Wb + (size_t)(bn + r0)*1024 + c0*8;
  const unsigned short* bS1 = Wb + (size_t)(bn + r1)*1024 + c1*8;
  unsigned short* aD0 = &As[0][0] + (wave*2+0)*512;
  unsigned short* aD1 = &As[0][0] + (wave*2+1)*512;
  unsigned short* bD0 = &Bs[0][0] + (wave*2+0)*512;
  unsigned short* bD1 = &Bs[0][0] + (wave*2+1)*512;

  const unsigned short* aR[4]; const unsigned short* bR[4];
  #pragma unroll
  for (int f=0; f<4; ++f){
    aR[f] = &As[wm*64 + f*16 + lr][kh*8];
    bR[f] = &Bs[wn*64 + f*16 + lr][kh*8];
  }

  f32x4 acc[4][4];
  #pragma unroll
  for (int i=0;i<4;++i)
    #pragma unroll
    for (int j=0;j<4;++j) acc[i][j] = (f32x4){0.f,0.f,0.f,0.f};

  for (int k0=0; k0<1024; k0+=32){
    __syncthreads();
    const size_t hoff = (size_t)(k0 >> 6)*(N_*DH_) + (k0 & 63);
    gload16(aBase0 + hoff, aD0);
    gload16(aBase1 + hoff, aD1);
    gload16(bS0 + k0, bD0);
    gload16(bS1 + k0, bD1);
    __syncthreads();
    bf16x8 af[4], bfr[4];
    #pragma unroll
    for (int f=0; f<4; ++f){
      af[f]  = *(const bf16x8*)aR[f];
      bfr[f] = *(const bf16x8*)bR[f];
    }
    __builtin_amdgcn_s_setprio(1);
    #pragma unroll
    for (int fm=0; fm<4; ++fm)
      #pragma unroll
      for (int fn=0; fn<4; ++fn)
        acc[fm][fn] = __builtin_amdgcn_mfma_f32_16x16x32_bf16(af[fm], bfr[fn], acc[fm][fn], 0,0,0);
    __builtin_amdgcn_s_setprio(0);
  }
  float bv[4];
  #pragma unroll
  for (int fn=0; fn<4; ++fn) bv[fn] = bias[bn + wn*64 + fn*16 + lr];
  #pragma unroll
  for (int fm=0; fm<4; ++fm){
    #pragma unroll
    for (int j=0; j<4; ++j){
      int m = bm + wm*64 + fm*16 + kh*4 + j;
      if (m >= M_) continue;
      #pragma unroll
      for (int fn=0; fn<4; ++fn){
        int c = bn + wn*64 + fn*16 + lr;
        out[(size_t)m*1024 + c] = acc[fm][fn][j] + bv[fn];
      }
    }
  }
}

// ---------------- kernel 4: score_delta int -> FP32 tail of d_out ----------------
__global__ void delta_to_f32(const int* __restrict__ delta, float* __restrict__ outd){
  int i = blockIdx.x*256 + threadIdx.x;
  if (i < H_*N_) outd[i] = (float)delta[i];
}

extern "C" void kernel_launch(void* const* d_in, const int* in_sizes, int n_in,
                              void* d_out, int out_size, void* d_ws, size_t ws_size,
                              hipStream_t stream) {
  const float* x      = (const float*)d_in[0];
  const float* qkv_w  = (const float*)d_in[1];
  const float* proj_w = (const float*)d_in[2];
  const float* proj_b = (const float*)d_in[3];
  const float* ucb    = (const float*)d_in[4];
  const int*   counter= (const int*)d_in[5];

  float* outO = (float*)d_out;
  float* outD = outO + ((size_t)out_size - (size_t)H_*N_);

  unsigned short* xb  = (unsigned short*)d_ws;        // M*C
  unsigned short* wqb = xb  + (size_t)M_*C_;          // 3*C*C
  unsigned short* wpb = wqb + (size_t)3*C_*C_;        // C*C
  unsigned short* qb  = wpb + (size_t)C_*C_;          // M*C (doubles as ctx)
  unsigned short* kb  = qb  + (size_t)M_*C_;
  unsigned short* vb  = kb  + (size_t)M_*C_;
  unsigned short* vt  = vb  + (size_t)M_*C_;          // 256*64*VTP
  int*         delta  = (int*)(vt + (size_t)B_*H_*DH_*VTP);

  hipMemsetAsync(delta, 0, (size_t)H_*N_*sizeof(int), stream);
  cvt_bf16<<<dim3(6664), 256, 0, stream>>>(x, qkv_w, proj_w, xb, wqb, wpb);
  gemm_qkv_mfma<<<dim3(73,24), 256, 0, stream>>>(xb, wqb, qb, kb, vb);
  transpose_v<<<dim3(2560), 256, 0, stream>>>(vb, vt);
  attn_kernel<<<dim3(256*37), 256, 0, stream>>>(qb, kb, vt, ucb, counter, qb /*ctx alias*/, delta);
  gemm_proj_mfma<<<dim3(73,8), 256, 0, stream>>>(qb, wpb, proj_b, outO);
  delta_to_f32<<<dim3(37), 256, 0, stream>>>(delta, outD);
}

// Round 14
// 364.568 us; speedup vs baseline: 1.0458x; 1.0458x over previous
//
#include <hip/hip_runtime.h>
#include <hip/hip_bf16.h>

#define B_ 16
#define N_ 577
#define C_ 1024
#define H_ 16
#define DH_ 64
#define M_ (B_*N_)          // 9232
#define KKEEP 144           // int(576 * 0.25)
#define VTP 584             // padded n-stride of transposed V
#define SST 325             // S row stride (dwords)

typedef __attribute__((ext_vector_type(8))) short bf16x8;
typedef __attribute__((ext_vector_type(4))) float f32x4;

// ---------------- helpers ----------------
__device__ __forceinline__ float b2f(unsigned short u){ return __uint_as_float(((unsigned int)u) << 16); }
__device__ __forceinline__ unsigned short f2bu(float f){
  __hip_bfloat16 h = __float2bfloat16(f);
  return *(unsigned short*)&h;
}
__device__ __forceinline__ float wredmaxf(float v){
  #pragma unroll
  for (int m=1;m<64;m<<=1) v = fmaxf(v, __shfl_xor(v, m, 64));
  return v;
}
__device__ __forceinline__ float wredsumf(float v){
  #pragma unroll
  for (int m=1;m<64;m<<=1) v += __shfl_xor(v, m, 64);
  return v;
}
// async global->LDS, 16B per lane; dest = uniform base + lane*16 (m104)
__device__ __forceinline__ void gload16(const unsigned short* g, unsigned short* l){
  __builtin_amdgcn_global_load_lds(
      (const __attribute__((address_space(1))) unsigned int*)g,
      (__attribute__((address_space(3))) unsigned int*)l,
      16, 0, 0);
}

// ---------------- kernel 0: fp32 -> bf16 pre-convert (X, qkv_w, proj_w) ----------------
__global__ __launch_bounds__(256) void cvt_bf16(
    const float* __restrict__ X, const float* __restrict__ Wq, const float* __restrict__ Wp,
    unsigned short* __restrict__ xb, unsigned short* __restrict__ wqb, unsigned short* __restrict__ wpb)
{
  size_t g = (size_t)blockIdx.x*256 + threadIdx.x;
  const float* src; unsigned short* dst; size_t off;
  if (g < 1181696){ src = X; dst = xb; off = g*8; }
  else if (g < 1574912){ src = Wq; dst = wqb; off = (g-1181696)*8; }
  else { src = Wp; dst = wpb; off = (g-1574912)*8; }
  float4 a = *(const float4*)(src+off), b = *(const float4*)(src+off+4);
  unsigned short t[8] = { f2bu(a.x), f2bu(a.y), f2bu(a.z), f2bu(a.w),
                          f2bu(b.x), f2bu(b.y), f2bu(b.z), f2bu(b.w) };
  *(uint4*)(dst+off) = *(uint4*)t;
}

// ---------------- kernel 1: QKV GEMM via MFMA + global_load_lds staging ----------------
// q output pre-scaled by 0.125 (exact power of two: bf16(x*0.125) == bf16(x)*0.125)
__global__ __launch_bounds__(256) void gemm_qkv_mfma(
    const unsigned short* __restrict__ Xb, const unsigned short* __restrict__ Wb,
    unsigned short* __restrict__ qb, unsigned short* __restrict__ kb,
    unsigned short* __restrict__ vb)
{
  __shared__ __align__(16) unsigned short As[128][32];   // 64B rows: bank-balanced b128 frags
  __shared__ __align__(16) unsigned short Bs[128][32];
  const int tid = threadIdx.x;
  const int lane = tid & 63, wave = tid >> 6;
  const int wm = wave >> 1, wn = wave & 1;
  const int lr = lane & 15, kh = lane >> 4;
  const int bm = blockIdx.x*128, bn = blockIdx.y*128;

  const int idx0 = (wave*2+0)*64 + lane;
  const int idx1 = (wave*2+1)*64 + lane;
  const int r0 = idx0 >> 2, c0 = idx0 & 3;
  const int r1 = idx1 >> 2, c1 = idx1 & 3;
  const unsigned short* aS0 = Xb + (size_t)(bm + r0)*1024 + c0*8;
  const unsigned short* aS1 = Xb + (size_t)(bm + r1)*1024 + c1*8;
  const unsigned short* bS0 = Wb + (size_t)(bn + r0)*1024 + c0*8;
  const unsigned short* bS1 = Wb + (size_t)(bn + r1)*1024 + c1*8;
  unsigned short* aD0 = &As[0][0] + (wave*2+0)*512;
  unsigned short* aD1 = &As[0][0] + (wave*2+1)*512;
  unsigned short* bD0 = &Bs[0][0] + (wave*2+0)*512;
  unsigned short* bD1 = &Bs[0][0] + (wave*2+1)*512;

  const unsigned short* aR[4]; const unsigned short* bR[4];
  #pragma unroll
  for (int f=0; f<4; ++f){
    aR[f] = &As[wm*64 + f*16 + lr][kh*8];
    bR[f] = &Bs[wn*64 + f*16 + lr][kh*8];
  }

  f32x4 acc[4][4];
  #pragma unroll
  for (int i=0;i<4;++i)
    #pragma unroll
    for (int j=0;j<4;++j) acc[i][j] = (f32x4){0.f,0.f,0.f,0.f};

  for (int k0=0; k0<1024; k0+=32){
    __syncthreads();
    gload16(aS0 + k0, aD0);
    gload16(aS1 + k0, aD1);
    gload16(bS0 + k0, bD0);
    gload16(bS1 + k0, bD1);
    __syncthreads();
    bf16x8 af[4], bfr[4];
    #pragma unroll
    for (int f=0; f<4; ++f){
      af[f]  = *(const bf16x8*)aR[f];
      bfr[f] = *(const bf16x8*)bR[f];
    }
    #pragma unroll
    for (int fm=0; fm<4; ++fm)
      #pragma unroll
      for (int fn=0; fn<4; ++fn)
        acc[fm][fn] = __builtin_amdgcn_mfma_f32_16x16x32_bf16(af[fm], bfr[fn], acc[fm][fn], 0,0,0);
  }
  #pragma unroll
  for (int fm=0; fm<4; ++fm){
    #pragma unroll
    for (int j=0; j<4; ++j){
      int m = bm + wm*64 + fm*16 + kh*4 + j;
      if (m >= M_) continue;
      int b = m / N_, n = m - b*N_;
      #pragma unroll
      for (int fn=0; fn<4; ++fn){
        int c = bn + wn*64 + fn*16 + lr;
        int three = c >> 10, hh = (c >> 6) & 15, dd = c & 63;
        size_t off = ((size_t)(b*H_ + hh)*N_ + n)*DH_ + dd;
        if (three == 0)      qb[off] = f2bu(acc[fm][fn][j]*0.125f);   // folded softmax scale
        else if (three == 1) kb[off] = f2bu(acc[fm][fn][j]);
        else                 vb[off] = f2bu(acc[fm][fn][j]);
      }
    }
  }
}

// ---------------- kernel 1b: V transpose [bh][n][64] -> [bh][d][VTP] ----------------
__global__ __launch_bounds__(256) void transpose_v(
    const unsigned short* __restrict__ vb, unsigned short* __restrict__ vt)
{
  __shared__ unsigned short tile[64][72];
  const int t = threadIdx.x;
  const int bh = blockIdx.x / 10, nt = blockIdx.x % 10;
  const int n0 = nt*64;
  {
    int r = t >> 2, c0 = (t & 3) * 16;
    int n = n0 + r;
    uint4 a0={0,0,0,0}, a1={0,0,0,0};
    if (n < N_){
      const uint4* s = (const uint4*)(vb + ((size_t)bh*N_ + n)*DH_ + c0);
      a0 = s[0]; a1 = s[1];
    }
    *(uint4*)&tile[r][c0]   = a0;
    *(uint4*)&tile[r][c0+8] = a1;
  }
  __syncthreads();
  {
    int d = t & 63, j0 = (t >> 6) * 16;
    unsigned short v[16];
    #pragma unroll
    for (int i=0;i<16;++i) v[i] = tile[j0+i][d];
    unsigned short* dst = vt + ((size_t)bh*DH_ + d)*VTP + n0 + j0;
    if (n0 + j0 + 15 <= VTP-1){
      *(uint4*)dst     = *(uint4*)&v[0];
      *(uint4*)(dst+8) = *(uint4*)&v[8];
    } else if (n0 + j0 + 7 <= VTP-1){
      *(uint4*)dst = *(uint4*)&v[0];
    }
  }
}

// ---------------- kernel 2: fused attention (r12 structure; scale pre-folded) ----------------
__global__ __launch_bounds__(256,6) void attn_kernel(
    const unsigned short* __restrict__ qw, const unsigned short* __restrict__ kw,
    const unsigned short* __restrict__ vt,
    const float* __restrict__ ucb, const int* __restrict__ counter_p,
    unsigned short* __restrict__ ctx, int* __restrict__ delta)
{
  __shared__ __align__(16) float S[16][SST];
  __shared__ float expl_s[584];
  __shared__ int   cnt_s[584];
  unsigned short (*pus)[584] = (unsigned short (*)[584])&S[0][0];

  const int tid = threadIdx.x;
  const int lane = tid & 63, wave = tid >> 6;
  const int lr = lane & 15, kh = lane >> 4;
  const int blk = blockIdx.x;
  const int bh = blk / 37, tileq = blk % 37;
  const int h = bh & 15;
  const int row0 = tileq * 16;

  const float logc = logf((float)(*counter_p) + 1.0f);
  for (int k2=tid; k2<N_; k2+=256){
    cnt_s[k2] = 0;
    expl_s[k2] = (k2==0) ? 0.f : sqrtf(logc / (ucb[h*N_ + k2] + 1e-6f));
  }

  const unsigned short* qbb = qw + (size_t)bh*N_*DH_;
  const unsigned short* kbb = kw + (size_t)bh*N_*DH_;
  bf16x8 aq0 = {0,0,0,0,0,0,0,0}, aq1 = {0,0,0,0,0,0,0,0};
  {
    int qr = row0 + lr;
    if (qr < N_){
      aq0 = *(const bf16x8*)(qbb + (size_t)qr*DH_ + kh*8);
      aq1 = *(const bf16x8*)(qbb + (size_t)qr*DH_ + 32 + kh*8);
    }
  }

  float acc[4][10];
  #pragma unroll
  for (int r=0;r<4;++r)
    #pragma unroll
    for (int s=0;s<10;++s) acc[r][s]=0.f;

  #pragma unroll
  for (int half=0; half<2; ++half){
    const int t0 = half ? 20 : 0, t1 = half ? 37 : 20, keyoff = half*320;
    for (int tile = t0 + wave; tile < t1; tile += 4){
      int keyr = tile*16 + lr;
      bf16x8 b0 = {0,0,0,0,0,0,0,0}, b1 = {0,0,0,0,0,0,0,0};
      if (keyr < N_){
        b0 = *(const bf16x8*)(kbb + (size_t)keyr*DH_ + kh*8);
        b1 = *(const bf16x8*)(kbb + (size_t)keyr*DH_ + 32 + kh*8);
      }
      f32x4 d = (f32x4){0.f,0.f,0.f,0.f};
      d = __builtin_amdgcn_mfma_f32_16x16x32_bf16(aq0, b0, d, 0,0,0);
      d = __builtin_amdgcn_mfma_f32_16x16x32_bf16(aq1, b1, d, 0,0,0);
      int col = tile*16 - keyoff + lr;
      #pragma unroll
      for (int rg=0; rg<4; ++rg)
        S[kh*4+rg][col] = d[rg];
    }
    __syncthreads();
    #pragma unroll
    for (int s=0; s<5; ++s){
      int sg = half*5 + s;
      int k = sg*64 + lane;
      if (k < N_){
        #pragma unroll
        for (int r=0;r<4;++r) acc[r][sg] = S[wave*4+r][k - keyoff];
      }
    }
    __syncthreads();
  }

  // ---- top-k (10-bit quantized ballot radix) + masked softmax + P store ----
  // scores already include the 0.125 scale (folded into q)
  #pragma unroll
  for (int r=0;r<4;++r){
    const int lrow = wave*4 + r;
    const int n = row0 + lrow;
    const bool rv = (n < N_);
    float uv[10]; bool vd[10];
    float mx0 = -3.4e38f, mn0 = 3.4e38f;
    #pragma unroll
    for (int s=0;s<10;++s){
      int k = s*64 + lane;
      vd[s] = (k >= 1) && (k < N_);
      uv[s] = acc[r][s] + (k < N_ ? expl_s[k] : 0.f);
      if (vd[s]){ mx0 = fmaxf(mx0, uv[s]); mn0 = fminf(mn0, uv[s]); }
    }
    const float mx1 = wredmaxf(mx0);
    const float mn1 = -wredmaxf(-mn0);
    const float scale = 1022.f / fmaxf(mx1 - mn1, 1e-30f);
    unsigned uq[10];
    #pragma unroll
    for (int s=0;s<10;++s)
      uq[s] = vd[s] ? (1u + (unsigned)((uv[s]-mn1)*scale)) : 0u;

    unsigned T = 0u;
    for (int bit=9; bit>=0; --bit){
      unsigned cand = T | (1u << bit);
      int c = 0;
      #pragma unroll
      for (int s=0;s<10;++s) c += (int)__popcll(__ballot(uq[s] >= cand));
      if (c >= KKEEP) T = cand;
    }
    int cgt = 0;
    #pragma unroll
    for (int s=0;s<10;++s) cgt += (int)__popcll(__ballot(uq[s] > T));
    const int rem = KKEEP - cgt;
    unsigned long long em[10];
    #pragma unroll
    for (int s=0;s<10;++s) em[s] = __ballot(uq[s] == T);
    const unsigned long long below = lane ? (~0ull >> (64 - lane)) : 0ull;
    bool keep[10];
    int pref = 0;
    #pragma unroll
    for (int s=0;s<10;++s){
      int k = s*64 + lane;
      bool kp2 = false;
      if (k == 0) kp2 = true;
      else if (k < N_){
        if (uq[s] > T) kp2 = true;
        else if (uq[s] == T) kp2 = (pref + __popcll(em[s] & below)) < rem;
      }
      keep[s] = kp2;
      pref += __popcll(em[s]);
    }
    float mxs = -3.4e38f;
    #pragma unroll
    for (int s=0;s<10;++s) if (keep[s]) mxs = fmaxf(mxs, acc[r][s]);
    mxs = wredmaxf(mxs);
    float p[10]; float den = 0.f;
    #pragma unroll
    for (int s=0;s<10;++s){ p[s] = keep[s] ? __expf(acc[r][s]-mxs) : 0.f; den += p[s]; }
    den = wredsumf(den);
    const float inv = 1.0f/den;
    #pragma unroll
    for (int s=0;s<10;++s){
      int k = s*64 + lane;
      if (k < N_) pus[lrow][k] = f2bu(p[s]*inv);
      if (rv && keep[s]) atomicAdd(&cnt_s[k < N_ ? k : 0], 1);
    }
  }
  __syncthreads();

  // ---- PV via MFMA ----
  {
    const int d0 = wave*16;
    const unsigned short* vtb = vt + ((size_t)bh*DH_ + d0 + lr)*VTP;
    f32x4 od = (f32x4){0.f,0.f,0.f,0.f};
    #pragma unroll 3
    for (int kb2=0; kb2<18; ++kb2){
      bf16x8 pa  = *(const bf16x8*)&pus[lr][kb2*32 + kh*8];
      bf16x8 vb8 = *(const bf16x8*)(vtb + kb2*32 + kh*8);
      od = __builtin_amdgcn_mfma_f32_16x16x32_bf16(pa, vb8, od, 0,0,0);
    }
    const float v576 = b2f(vtb[576]);
    #pragma unroll
    for (int rg=0; rg<4; ++rg){
      int q = kh*4 + rg;
      float o = fmaf(b2f(pus[q][576]), v576, od[rg]);
      int n0 = row0 + q;
      if (n0 < N_) ctx[((size_t)bh*N_ + n0)*DH_ + d0 + lr] = f2bu(o);
    }
  }
  __syncthreads();
  for (int k2=tid; k2<N_; k2+=256){
    int c2 = cnt_s[k2];
    if (c2) atomicAdd(&delta[h*N_ + k2], c2);
  }
}

// ---------------- kernel 3: output projection via MFMA + global_load_lds ----------------
__global__ __launch_bounds__(256) void gemm_proj_mfma(
    const unsigned short* __restrict__ ctxp, const unsigned short* __restrict__ Wb,
    const float* __restrict__ bias, float* __restrict__ out)
{
  __shared__ __align__(16) unsigned short As[128][32];
  __shared__ __align__(16) unsigned short Bs[128][32];
  const int tid = threadIdx.x;
  const int lane = tid & 63, wave = tid >> 6;
  const int wm = wave >> 1, wn = wave & 1;
  const int lr = lane & 15, kh = lane >> 4;
  const int bm = blockIdx.x*128, bn = blockIdx.y*128;

  const int idx0 = (wave*2+0)*64 + lane;
  const int idx1 = (wave*2+1)*64 + lane;
  const int r0 = idx0 >> 2, c0 = idx0 & 3;
  const int r1 = idx1 >> 2, c1 = idx1 & 3;
  const int m0r = bm + r0, m1r = bm + r1;
  const int b0 = m0r / N_, n0r = m0r - b0*N_;
  const int b1 = m1r / N_, n1r = m1r - b1*N_;
  const unsigned short* aBase0 = ctxp + ((size_t)b0*H_*N_ + n0r)*DH_ + c0*8;
  const unsigned short* aBase1 = ctxp + ((size_t)b1*H_*N_ + n1r)*DH_ + c1*8;
  const unsigned short* bS0 = Wb + (size_t)(bn + r0)*1024 + c0*8;
  const unsigned short* bS1 = Wb + (size_t)(bn + r1)*1024 + c1*8;
  unsigned short* aD0 = &As[0][0] + (wave*2+0)*512;
  unsigned short* aD1 = &As[0][0] + (wave*2+1)*512;
  unsigned short* bD0 = &Bs[0][0] + (wave*2+0)*512;
  unsigned short* bD1 = &Bs[0][0] + (wave*2+1)*512;

  const unsigned short* aR[4]; const unsigned short* bR[4];
  #pragma unroll
  for (int f=0; f<4; ++f){
    aR[f] = &As[wm*64 + f*16 + lr][kh*8];
    bR[f] = &Bs[wn*64 + f*16 + lr][kh*8];
  }

  f32x4 acc[4][4];
  #pragma unroll
  for (int i=0;i<4;++i)
    #pragma unroll
    for (int j=0;j<4;++j) acc[i][j] = (f32x4){0.f,0.f,0.f,0.f};

  for (int k0=0; k0<1024; k0+=32){
    __syncthreads();
    const size_t hoff = (size_t)(k0 >> 6)*(N_*DH_) + (k0 & 63);
    gload16(aBase0 + hoff, aD0);
    gload16(aBase1 + hoff, aD1);
    gload16(bS0 + k0, bD0);
    gload16(bS1 + k0, bD1);
    __syncthreads();
    bf16x8 af[4], bfr[4];
    #pragma unroll
    for (int f=0; f<4; ++f){
      af[f]  = *(const bf16x8*)aR[f];
      bfr[f] = *(const bf16x8*)bR[f];
    }
    #pragma unroll
    for (int fm=0; fm<4; ++fm)
      #pragma unroll
      for (int fn=0; fn<4; ++fn)
        acc[fm][fn] = __builtin_amdgcn_mfma_f32_16x16x32_bf16(af[fm], bfr[fn], acc[fm][fn], 0,0,0);
  }
  float bv[4];
  #pragma unroll
  for (int fn=0; fn<4; ++fn) bv[fn] = bias[bn + wn*64 + fn*16 + lr];
  #pragma unroll
  for (int fm=0; fm<4; ++fm){
    #pragma unroll
    for (int j=0; j<4; ++j){
      int m = bm + wm*64 + fm*16 + kh*4 + j;
      if (m >= M_) continue;
      #pragma unroll
      for (int fn=0; fn<4; ++fn){
        int c = bn + wn*64 + fn*16 + lr;
        out[(size_t)m*1024 + c] = acc[fm][fn][j] + bv[fn];
      }
    }
  }
}

// ---------------- kernel 4: score_delta int -> FP32 tail of d_out ----------------
__global__ void delta_to_f32(const int* __restrict__ delta, float* __restrict__ outd){
  int i = blockIdx.x*256 + threadIdx.x;
  if (i < H_*N_) outd[i] = (float)delta[i];
}

extern "C" void kernel_launch(void* const* d_in, const int* in_sizes, int n_in,
                              void* d_out, int out_size, void* d_ws, size_t ws_size,
                              hipStream_t stream) {
  const float* x      = (const float*)d_in[0];
  const float* qkv_w  = (const float*)d_in[1];
  const float* proj_w = (const float*)d_in[2];
  const float* proj_b = (const float*)d_in[3];
  const float* ucb    = (const float*)d_in[4];
  const int*   counter= (const int*)d_in[5];

  float* outO = (float*)d_out;
  float* outD = outO + ((size_t)out_size - (size_t)H_*N_);

  unsigned short* xb  = (unsigned short*)d_ws;        // M*C
  unsigned short* wqb = xb  + (size_t)M_*C_;          // 3*C*C
  unsigned short* wpb = wqb + (size_t)3*C_*C_;        // C*C
  unsigned short* qb  = wpb + (size_t)C_*C_;          // M*C (doubles as ctx)
  unsigned short* kb  = qb  + (size_t)M_*C_;
  unsigned short* vb  = kb  + (size_t)M_*C_;
  unsigned short* vt  = vb  + (size_t)M_*C_;          // 256*64*VTP
  int*         delta  = (int*)(vt + (size_t)B_*H_*DH_*VTP);

  hipMemsetAsync(delta, 0, (size_t)H_*N_*sizeof(int), stream);
  cvt_bf16<<<dim3(6664), 256, 0, stream>>>(x, qkv_w, proj_w, xb, wqb, wpb);
  gemm_qkv_mfma<<<dim3(73,24), 256, 0, stream>>>(xb, wqb, qb, kb, vb);
  transpose_v<<<dim3(2560), 256, 0, stream>>>(vb, vt);
  attn_kernel<<<dim3(256*37), 256, 0, stream>>>(qb, kb, vt, ucb, counter, qb /*ctx alias*/, delta);
  gemm_proj_mfma<<<dim3(73,8), 256, 0, stream>>>(qb, wpb, proj_b, outO);
  delta_to_f32<<<dim3(37), 256, 0, stream>>>(delta, outD);
}

// Round 15
// 363.501 us; speedup vs baseline: 1.0489x; 1.0029x over previous
//
#include <hip/hip_runtime.h>
#include <hip/hip_bf16.h>

#define B_ 16
#define N_ 577
#define C_ 1024
#define H_ 16
#define DH_ 64
#define M_ (B_*N_)          // 9232
#define KKEEP 144           // int(576 * 0.25)
#define VTP 584             // padded n-stride of transposed V
#define SST 325             // S row stride (dwords)

typedef __attribute__((ext_vector_type(8))) short bf16x8;
typedef __attribute__((ext_vector_type(4))) float f32x4;

// ---------------- helpers ----------------
__device__ __forceinline__ float b2f(unsigned short u){ return __uint_as_float(((unsigned int)u) << 16); }
__device__ __forceinline__ unsigned short f2bu(float f){
  __hip_bfloat16 h = __float2bfloat16(f);
  return *(unsigned short*)&h;
}
__device__ __forceinline__ float wredmaxf(float v){
  #pragma unroll
  for (int m=1;m<64;m<<=1) v = fmaxf(v, __shfl_xor(v, m, 64));
  return v;
}
__device__ __forceinline__ float wredsumf(float v){
  #pragma unroll
  for (int m=1;m<64;m<<=1) v += __shfl_xor(v, m, 64);
  return v;
}
// async global->LDS, 16B per lane; dest = uniform base + lane*16 (m104)
__device__ __forceinline__ void gload16(const unsigned short* g, unsigned short* l){
  __builtin_amdgcn_global_load_lds(
      (const __attribute__((address_space(1))) unsigned int*)g,
      (__attribute__((address_space(3))) unsigned int*)l,
      16, 0, 0);
}

// ---------------- kernel 0: fp32 -> bf16 pre-convert (X, qkv_w, proj_w) ----------------
__global__ __launch_bounds__(256) void cvt_bf16(
    const float* __restrict__ X, const float* __restrict__ Wq, const float* __restrict__ Wp,
    unsigned short* __restrict__ xb, unsigned short* __restrict__ wqb, unsigned short* __restrict__ wpb)
{
  size_t g = (size_t)blockIdx.x*256 + threadIdx.x;
  const float* src; unsigned short* dst; size_t off;
  if (g < 1181696){ src = X; dst = xb; off = g*8; }
  else if (g < 1574912){ src = Wq; dst = wqb; off = (g-1181696)*8; }
  else { src = Wp; dst = wpb; off = (g-1574912)*8; }
  float4 a = *(const float4*)(src+off), b = *(const float4*)(src+off+4);
  unsigned short t[8] = { f2bu(a.x), f2bu(a.y), f2bu(a.z), f2bu(a.w),
                          f2bu(b.x), f2bu(b.y), f2bu(b.z), f2bu(b.w) };
  *(uint4*)(dst+off) = *(uint4*)t;
}

// ---------------- kernel 1: QKV GEMM via MFMA + global_load_lds staging ----------------
// q output pre-scaled by 0.125 (exact power of two: bf16(x*0.125) == bf16(x)*0.125)
__global__ __launch_bounds__(256) void gemm_qkv_mfma(
    const unsigned short* __restrict__ Xb, const unsigned short* __restrict__ Wb,
    unsigned short* __restrict__ qb, unsigned short* __restrict__ kb,
    unsigned short* __restrict__ vb)
{
  __shared__ __align__(16) unsigned short As[128][32];   // 64B rows: bank-balanced b128 frags
  __shared__ __align__(16) unsigned short Bs[128][32];
  const int tid = threadIdx.x;
  const int lane = tid & 63, wave = tid >> 6;
  const int wm = wave >> 1, wn = wave & 1;
  const int lr = lane & 15, kh = lane >> 4;
  const int bm = blockIdx.x*128, bn = blockIdx.y*128;

  const int idx0 = (wave*2+0)*64 + lane;
  const int idx1 = (wave*2+1)*64 + lane;
  const int r0 = idx0 >> 2, c0 = idx0 & 3;
  const int r1 = idx1 >> 2, c1 = idx1 & 3;
  const unsigned short* aS0 = Xb + (size_t)(bm + r0)*1024 + c0*8;
  const unsigned short* aS1 = Xb + (size_t)(bm + r1)*1024 + c1*8;
  const unsigned short* bS0 = Wb + (size_t)(bn + r0)*1024 + c0*8;
  const unsigned short* bS1 = Wb + (size_t)(bn + r1)*1024 + c1*8;
  unsigned short* aD0 = &As[0][0] + (wave*2+0)*512;
  unsigned short* aD1 = &As[0][0] + (wave*2+1)*512;
  unsigned short* bD0 = &Bs[0][0] + (wave*2+0)*512;
  unsigned short* bD1 = &Bs[0][0] + (wave*2+1)*512;

  const unsigned short* aR[4]; const unsigned short* bR[4];
  #pragma unroll
  for (int f=0; f<4; ++f){
    aR[f] = &As[wm*64 + f*16 + lr][kh*8];
    bR[f] = &Bs[wn*64 + f*16 + lr][kh*8];
  }

  f32x4 acc[4][4];
  #pragma unroll
  for (int i=0;i<4;++i)
    #pragma unroll
    for (int j=0;j<4;++j) acc[i][j] = (f32x4){0.f,0.f,0.f,0.f};

  for (int k0=0; k0<1024; k0+=32){
    __syncthreads();
    gload16(aS0 + k0, aD0);
    gload16(aS1 + k0, aD1);
    gload16(bS0 + k0, bD0);
    gload16(bS1 + k0, bD1);
    __syncthreads();
    bf16x8 af[4], bfr[4];
    #pragma unroll
    for (int f=0; f<4; ++f){
      af[f]  = *(const bf16x8*)aR[f];
      bfr[f] = *(const bf16x8*)bR[f];
    }
    #pragma unroll
    for (int fm=0; fm<4; ++fm)
      #pragma unroll
      for (int fn=0; fn<4; ++fn)
        acc[fm][fn] = __builtin_amdgcn_mfma_f32_16x16x32_bf16(af[fm], bfr[fn], acc[fm][fn], 0,0,0);
  }
  #pragma unroll
  for (int fm=0; fm<4; ++fm){
    #pragma unroll
    for (int j=0; j<4; ++j){
      int m = bm + wm*64 + fm*16 + kh*4 + j;
      if (m >= M_) continue;
      int b = m / N_, n = m - b*N_;
      #pragma unroll
      for (int fn=0; fn<4; ++fn){
        int c = bn + wn*64 + fn*16 + lr;
        int three = c >> 10, hh = (c >> 6) & 15, dd = c & 63;
        size_t off = ((size_t)(b*H_ + hh)*N_ + n)*DH_ + dd;
        if (three == 0)      qb[off] = f2bu(acc[fm][fn][j]*0.125f);   // folded softmax scale
        else if (three == 1) kb[off] = f2bu(acc[fm][fn][j]);
        else                 vb[off] = f2bu(acc[fm][fn][j]);
      }
    }
  }
}

// ---------------- kernel 1b: V transpose [bh][n][64] -> [bh][d][VTP] ----------------
__global__ __launch_bounds__(256) void transpose_v(
    const unsigned short* __restrict__ vb, unsigned short* __restrict__ vt)
{
  __shared__ unsigned short tile[64][72];
  const int t = threadIdx.x;
  const int bh = blockIdx.x / 10, nt = blockIdx.x % 10;
  const int n0 = nt*64;
  {
    int r = t >> 2, c0 = (t & 3) * 16;
    int n = n0 + r;
    uint4 a0={0,0,0,0}, a1={0,0,0,0};
    if (n < N_){
      const uint4* s = (const uint4*)(vb + ((size_t)bh*N_ + n)*DH_ + c0);
      a0 = s[0]; a1 = s[1];
    }
    *(uint4*)&tile[r][c0]   = a0;
    *(uint4*)&tile[r][c0+8] = a1;
  }
  __syncthreads();
  {
    int d = t & 63, j0 = (t >> 6) * 16;
    unsigned short v[16];
    #pragma unroll
    for (int i=0;i<16;++i) v[i] = tile[j0+i][d];
    unsigned short* dst = vt + ((size_t)bh*DH_ + d)*VTP + n0 + j0;
    if (n0 + j0 + 15 <= VTP-1){
      *(uint4*)dst     = *(uint4*)&v[0];
      *(uint4*)(dst+8) = *(uint4*)&v[8];
    } else if (n0 + j0 + 7 <= VTP-1){
      *(uint4*)dst = *(uint4*)&v[0];
    }
  }
}

// ---------------- kernel 2: fused attention (wave-aggregated counts, float delta) ----------------
__global__ __launch_bounds__(256,6) void attn_kernel(
    const unsigned short* __restrict__ qw, const unsigned short* __restrict__ kw,
    const unsigned short* __restrict__ vt,
    const float* __restrict__ ucb, const int* __restrict__ counter_p,
    unsigned short* __restrict__ ctx, float* __restrict__ deltaf)
{
  __shared__ __align__(16) float S[16][SST];
  __shared__ float expl_s[584];
  __shared__ int   cnt_s[584];
  unsigned short (*pus)[584] = (unsigned short (*)[584])&S[0][0];

  const int tid = threadIdx.x;
  const int lane = tid & 63, wave = tid >> 6;
  const int lr = lane & 15, kh = lane >> 4;
  const int blk = blockIdx.x;
  const int bh = blk / 37, tileq = blk % 37;
  const int h = bh & 15;
  const int row0 = tileq * 16;

  const float logc = logf((float)(*counter_p) + 1.0f);
  for (int k2=tid; k2<N_; k2+=256){
    cnt_s[k2] = 0;
    expl_s[k2] = (k2==0) ? 0.f : sqrtf(logc / (ucb[h*N_ + k2] + 1e-6f));
  }

  const unsigned short* qbb = qw + (size_t)bh*N_*DH_;
  const unsigned short* kbb = kw + (size_t)bh*N_*DH_;
  bf16x8 aq0 = {0,0,0,0,0,0,0,0}, aq1 = {0,0,0,0,0,0,0,0};
  {
    int qr = row0 + lr;
    if (qr < N_){
      aq0 = *(const bf16x8*)(qbb + (size_t)qr*DH_ + kh*8);
      aq1 = *(const bf16x8*)(qbb + (size_t)qr*DH_ + 32 + kh*8);
    }
  }

  float acc[4][10];
  #pragma unroll
  for (int r=0;r<4;++r)
    #pragma unroll
    for (int s=0;s<10;++s) acc[r][s]=0.f;

  #pragma unroll
  for (int half=0; half<2; ++half){
    const int t0 = half ? 20 : 0, t1 = half ? 37 : 20, keyoff = half*320;
    for (int tile = t0 + wave; tile < t1; tile += 4){
      int keyr = tile*16 + lr;
      bf16x8 b0 = {0,0,0,0,0,0,0,0}, b1 = {0,0,0,0,0,0,0,0};
      if (keyr < N_){
        b0 = *(const bf16x8*)(kbb + (size_t)keyr*DH_ + kh*8);
        b1 = *(const bf16x8*)(kbb + (size_t)keyr*DH_ + 32 + kh*8);
      }
      f32x4 d = (f32x4){0.f,0.f,0.f,0.f};
      d = __builtin_amdgcn_mfma_f32_16x16x32_bf16(aq0, b0, d, 0,0,0);
      d = __builtin_amdgcn_mfma_f32_16x16x32_bf16(aq1, b1, d, 0,0,0);
      int col = tile*16 - keyoff + lr;
      #pragma unroll
      for (int rg=0; rg<4; ++rg)
        S[kh*4+rg][col] = d[rg];
    }
    __syncthreads();
    #pragma unroll
    for (int s=0; s<5; ++s){
      int sg = half*5 + s;
      int k = sg*64 + lane;
      if (k < N_){
        #pragma unroll
        for (int r=0;r<4;++r) acc[r][sg] = S[wave*4+r][k - keyoff];
      }
    }
    __syncthreads();
  }

  // ---- top-k (10-bit quantized ballot radix) + masked softmax + P store ----
  int cntl[10];
  #pragma unroll
  for (int s=0;s<10;++s) cntl[s] = 0;

  #pragma unroll
  for (int r=0;r<4;++r){
    const int lrow = wave*4 + r;
    const int n = row0 + lrow;
    const bool rv = (n < N_);
    float uv[10]; bool vd[10];
    float mx0 = -3.4e38f, mn0 = 3.4e38f;
    #pragma unroll
    for (int s=0;s<10;++s){
      int k = s*64 + lane;
      vd[s] = (k >= 1) && (k < N_);
      uv[s] = acc[r][s] + (k < N_ ? expl_s[k] : 0.f);
      if (vd[s]){ mx0 = fmaxf(mx0, uv[s]); mn0 = fminf(mn0, uv[s]); }
    }
    const float mx1 = wredmaxf(mx0);
    const float mn1 = -wredmaxf(-mn0);
    const float scale = 1022.f / fmaxf(mx1 - mn1, 1e-30f);
    unsigned uq[10];
    #pragma unroll
    for (int s=0;s<10;++s)
      uq[s] = vd[s] ? (1u + (unsigned)((uv[s]-mn1)*scale)) : 0u;

    unsigned T = 0u;
    for (int bit=9; bit>=0; --bit){
      unsigned cand = T | (1u << bit);
      int c = 0;
      #pragma unroll
      for (int s=0;s<10;++s) c += (int)__popcll(__ballot(uq[s] >= cand));
      if (c >= KKEEP) T = cand;
    }
    int cgt = 0;
    #pragma unroll
    for (int s=0;s<10;++s) cgt += (int)__popcll(__ballot(uq[s] > T));
    const int rem = KKEEP - cgt;
    unsigned long long em[10];
    #pragma unroll
    for (int s=0;s<10;++s) em[s] = __ballot(uq[s] == T);
    const unsigned long long below = lane ? (~0ull >> (64 - lane)) : 0ull;
    bool keep[10];
    int pref = 0;
    #pragma unroll
    for (int s=0;s<10;++s){
      int k = s*64 + lane;
      bool kp2 = false;
      if (k == 0) kp2 = true;
      else if (k < N_){
        if (uq[s] > T) kp2 = true;
        else if (uq[s] == T) kp2 = (pref + __popcll(em[s] & below)) < rem;
      }
      keep[s] = kp2;
      pref += __popcll(em[s]);
    }
    #pragma unroll
    for (int s=0;s<10;++s) cntl[s] += (rv && keep[s]) ? 1 : 0;

    float mxs = -3.4e38f;
    #pragma unroll
    for (int s=0;s<10;++s) if (keep[s]) mxs = fmaxf(mxs, acc[r][s]);
    mxs = wredmaxf(mxs);
    float p[10]; float den = 0.f;
    #pragma unroll
    for (int s=0;s<10;++s){ p[s] = keep[s] ? __expf(acc[r][s]-mxs) : 0.f; den += p[s]; }
    den = wredsumf(den);
    const float inv = 1.0f/den;
    #pragma unroll
    for (int s=0;s<10;++s){
      int k = s*64 + lane;
      if (k < N_) pus[lrow][k] = f2bu(p[s]*inv);
    }
  }
  // wave-aggregated count flush: one predicated LDS atomic per slot (value 0..4)
  #pragma unroll
  for (int s=0;s<10;++s){
    int k = s*64 + lane;
    if (k < N_ && cntl[s]) atomicAdd(&cnt_s[k], cntl[s]);
  }
  __syncthreads();

  // ---- PV via MFMA ----
  {
    const int d0 = wave*16;
    const unsigned short* vtb = vt + ((size_t)bh*DH_ + d0 + lr)*VTP;
    f32x4 od = (f32x4){0.f,0.f,0.f,0.f};
    #pragma unroll 3
    for (int kb2=0; kb2<18; ++kb2){
      bf16x8 pa  = *(const bf16x8*)&pus[lr][kb2*32 + kh*8];
      bf16x8 vb8 = *(const bf16x8*)(vtb + kb2*32 + kh*8);
      od = __builtin_amdgcn_mfma_f32_16x16x32_bf16(pa, vb8, od, 0,0,0);
    }
    const float v576 = b2f(vtb[576]);
    #pragma unroll
    for (int rg=0; rg<4; ++rg){
      int q = kh*4 + rg;
      float o = fmaf(b2f(pus[q][576]), v576, od[rg]);
      int n0 = row0 + q;
      if (n0 < N_) ctx[((size_t)bh*N_ + n0)*DH_ + d0 + lr] = f2bu(o);
    }
  }
  __syncthreads();
  // flush block counts straight to the fp32 delta tail of d_out (exact: counts << 2^24)
  for (int k2=tid; k2<N_; k2+=256){
    int c2 = cnt_s[k2];
    if (c2) atomicAdd(&deltaf[h*N_ + k2], (float)c2);
  }
}

// ---------------- kernel 3: output projection via MFMA + global_load_lds ----------------
__global__ __launch_bounds__(256) void gemm_proj_mfma(
    const unsigned short* __restrict__ ctxp, const unsigned short* __restrict__ Wb,
    const float* __restrict__ bias, float* __restrict__ out)
{
  __shared__ __align__(16) unsigned short As[128][32];
  __shared__ __align__(16) unsigned short Bs[128][32];
  const int tid = threadIdx.x;
  const int lane = tid & 63, wave = tid >> 6;
  const int wm = wave >> 1, wn = wave & 1;
  const int lr = lane & 15, kh = lane >> 4;
  const int bm = blockIdx.x*128, bn = blockIdx.y*128;

  const int idx0 = (wave*2+0)*64 + lane;
  const int idx1 = (wave*2+1)*64 + lane;
  const int r0 = idx0 >> 2, c0 = idx0 & 3;
  const int r1 = idx1 >> 2, c1 = idx1 & 3;
  const int m0r = bm + r0, m1r = bm + r1;
  const int b0 = m0r / N_, n0r = m0r - b0*N_;
  const int b1 = m1r / N_, n1r = m1r - b1*N_;
  const unsigned short* aBase0 = ctxp + ((size_t)b0*H_*N_ + n0r)*DH_ + c0*8;
  const unsigned short* aBase1 = ctxp + ((size_t)b1*H_*N_ + n1r)*DH_ + c1*8;
  const unsigned short* bS0 = Wb + (size_t)(bn + r0)*1024 + c0*8;
  const unsigned short* bS1 = Wb + (size_t)(bn + r1)*1024 + c1*8;
  unsigned short* aD0 = &As[0][0] + (wave*2+0)*512;
  unsigned short* aD1 = &As[0][0] + (wave*2+1)*512;
  unsigned short* bD0 = &Bs[0][0] + (wave*2+0)*512;
  unsigned short* bD1 = &Bs[0][0] + (wave*2+1)*512;

  const unsigned short* aR[4]; const unsigned short* bR[4];
  #pragma unroll
  for (int f=0; f<4; ++f){
    aR[f] = &As[wm*64 + f*16 + lr][kh*8];
    bR[f] = &Bs[wn*64 + f*16 + lr][kh*8];
  }

  f32x4 acc[4][4];
  #pragma unroll
  for (int i=0;i<4;++i)
    #pragma unroll
    for (int j=0;j<4;++j) acc[i][j] = (f32x4){0.f,0.f,0.f,0.f};

  for (int k0=0; k0<1024; k0+=32){
    __syncthreads();
    const size_t hoff = (size_t)(k0 >> 6)*(N_*DH_) + (k0 & 63);
    gload16(aBase0 + hoff, aD0);
    gload16(aBase1 + hoff, aD1);
    gload16(bS0 + k0, bD0);
    gload16(bS1 + k0, bD1);
    __syncthreads();
    bf16x8 af[4], bfr[4];
    #pragma unroll
    for (int f=0; f<4; ++f){
      af[f]  = *(const bf16x8*)aR[f];
      bfr[f] = *(const bf16x8*)bR[f];
    }
    #pragma unroll
    for (int fm=0; fm<4; ++fm)
      #pragma unroll
      for (int fn=0; fn<4; ++fn)
        acc[fm][fn] = __builtin_amdgcn_mfma_f32_16x16x32_bf16(af[fm], bfr[fn], acc[fm][fn], 0,0,0);
  }
  float bv[4];
  #pragma unroll
  for (int fn=0; fn<4; ++fn) bv[fn] = bias[bn + wn*64 + fn*16 + lr];
  #pragma unroll
  for (int fm=0; fm<4; ++fm){
    #pragma unroll
    for (int j=0; j<4; ++j){
      int m = bm + wm*64 + fm*16 + kh*4 + j;
      if (m >= M_) continue;
      #pragma unroll
      for (int fn=0; fn<4; ++fn){
        int c = bn + wn*64 + fn*16 + lr;
        out[(size_t)m*1024 + c] = acc[fm][fn][j] + bv[fn];
      }
    }
  }
}

extern "C" void kernel_launch(void* const* d_in, const int* in_sizes, int n_in,
                              void* d_out, int out_size, void* d_ws, size_t ws_size,
                              hipStream_t stream) {
  const float* x      = (const float*)d_in[0];
  const float* qkv_w  = (const float*)d_in[1];
  const float* proj_w = (const float*)d_in[2];
  const float* proj_b = (const float*)d_in[3];
  const float* ucb    = (const float*)d_in[4];
  const int*   counter= (const int*)d_in[5];

  float* outO = (float*)d_out;
  float* outD = outO + ((size_t)out_size - (size_t)H_*N_);

  unsigned short* xb  = (unsigned short*)d_ws;        // M*C
  unsigned short* wqb = xb  + (size_t)M_*C_;          // 3*C*C
  unsigned short* wpb = wqb + (size_t)3*C_*C_;        // C*C
  unsigned short* qb  = wpb + (size_t)C_*C_;          // M*C (doubles as ctx)
  unsigned short* kb  = qb  + (size_t)M_*C_;
  unsigned short* vb  = kb  + (size_t)M_*C_;
  unsigned short* vt  = vb  + (size_t)M_*C_;          // 256*64*VTP
  // int delta buffer no longer needed: attn accumulates fp32 directly into d_out tail

  hipMemsetAsync(outD, 0, (size_t)H_*N_*sizeof(float), stream);
  cvt_bf16<<<dim3(6664), 256, 0, stream>>>(x, qkv_w, proj_w, xb, wqb, wpb);
  gemm_qkv_mfma<<<dim3(73,24), 256, 0, stream>>>(xb, wqb, qb, kb, vb);
  transpose_v<<<dim3(2560), 256, 0, stream>>>(vb, vt);
  attn_kernel<<<dim3(256*37), 256, 0, stream>>>(qb, kb, vt, ucb, counter, qb /*ctx alias*/, outD);
  gemm_proj_mfma<<<dim3(73,8), 256, 0, stream>>>(qb, wpb, proj_b, outO);
}